// Round 8
// baseline (1426.957 us; speedup 1.0000x reference)
//
#include <hip/hip_runtime.h>

namespace {

constexpr int T = 1024;
constexpr int B = 1024;
constexpr int L = 10;
constexpr int H = 10;
constexpr int NTHREADS = 256;           // 4 waves; 200 active threads
constexpr int NSTEP = T + L - 1;        // 1033
constexpr int BH = B * H;
constexpr int CH = 8;                   // x-prefetch chunk (drain amortization)
constexpr int NCHUNK = (NSTEP + CH - 1) / CH;   // 130

using v2f = __attribute__((ext_vector_type(2))) float;

__device__ __forceinline__ v2f v2fma(v2f a, v2f b, v2f c) {
    return __builtin_elementwise_fma(a, b, c);
}

// Swap adjacent lanes (2k <-> 2k+1) via DPP quad_perm [1,0,3,2]: 1 VALU op,
// no LDS. Pairs never straddle a wave (even/odd lanes).
__device__ __forceinline__ float lane_swap(float v) {
    int i = __builtin_bit_cast(int, v);
    i = __builtin_amdgcn_mov_dpp(i, 0xB1, 0xF, 0xF, true);
    return __builtin_bit_cast(float, i);
}

__device__ __forceinline__ float sigmoid_f(float x) {
    return __builtin_amdgcn_rcpf(1.0f + __expf(-x));
}
__device__ __forceinline__ float tanh_f(float x) {
    return 1.0f - 2.0f * __builtin_amdgcn_rcpf(1.0f + __expf(2.0f * x));
}

// Thread = (layer, unit, half). hsel0 owns the W_ih dot (+bias) and the
// c-chain; hsel1 owns the W_hh dot and the h-write. Gate order i,f,g,o:
// hsel0 keeps gates {i,g}, hsel1 keeps {f,o}; each lane sends its partials
// of the partner's gates via one DPP swap per gate pair.
__global__
__attribute__((amdgpu_flat_work_group_size(NTHREADS, NTHREADS)))
__attribute__((amdgpu_waves_per_eu(4, 4)))   // 128-VGPR budget, 16 waves/CU
void lstm_pipeline(const float* __restrict__ x,    // [T,B,H]
                   const float* __restrict__ hp,   // [L,B,H]
                   const float* __restrict__ cp,   // [L,B,H]
                   const float* __restrict__ Wih,  // [L,4H,H]
                   const float* __restrict__ Whh,  // [L,4H,H]
                   const float* __restrict__ bih,  // [L,4H]
                   const float* __restrict__ bhh,  // [L,4H]
                   float* __restrict__ out,        // [T,B,H]
                   float* __restrict__ hn,         // [L,B,H]
                   float* __restrict__ cn)         // [L,B,H]
{
    // buf[l] = input to layer l (l=0: staged x; l>=1: h of layer l-1).
    // s-parity double buffer; rows padded 10->12 floats for float4 reads.
    __shared__ __align__(16) float buf[L + 1][2][12];

    const int tid = threadIdx.x;
    const bool active = tid < L * H * 2;
    const int l    = active ? tid / (2 * H) : L - 1;         // layer 0..9
    const int j    = active ? (tid % (2 * H)) >> 1 : H - 1;  // unit 0..9
    const bool hsel = tid & 1;               // 0: x-side (W_ih), 1: h-side (W_hh)
    const int b = blockIdx.x;
    const int boff = b * H + j;

    // This half's 4 gate rows (i,f,g,o) of W_ih or W_hh: 20 v2f = 40 VGPRs.
    v2f w2[4][5];
    float bias[4];
    float c = 0.0f;
    float xcur[CH], xnext[CH];

    if (active) {
        const float* Wsel = hsel ? Whh : Wih;
        #pragma unroll
        for (int g = 0; g < 4; ++g) {
            const size_t row = (size_t)(l * 4 * H + g * H + j);
            const float* wr = Wsel + row * H;
            #pragma unroll
            for (int p = 0; p < 5; ++p) {
                v2f a; a[0] = wr[2 * p]; a[1] = wr[2 * p + 1]; w2[g][p] = a;
            }
            bias[g] = hsel ? 0.0f : (bih[row] + bhh[row]);  // bias on x-side half
        }
        c = cp[(l * B + b) * H + j];         // meaningful on hsel==0 only
        if (hsel) {
            // h(-1): layer l reads it at s=l from parity (l-1)&1.
            buf[l + 1][(l & 1) ^ 1][j] = hp[(l * B + b) * H + j];
        }
        if (l == 0 && !hsel) {
            buf[0][1][j] = x[boff];          // x(0), read at s=0 (parity 1)
            #pragma unroll
            for (int i = 0; i < CH; ++i) xcur[i] = x[(size_t)(1 + i) * BH + boff];
        }
    }
    // Second-activation constants: hsel0 -> tanh(g) = 1 - 2*rcp(1+exp(2x));
    // hsel1 -> sigmoid(o) = 0 + 1*rcp(1+exp(-x)).
    const float k2 = hsel ? -1.0f : 2.0f;
    const float A2 = hsel ? 0.0f : 1.0f;
    const float B2 = hsel ? -1.0f : 2.0f;
    __syncthreads();

    auto step = [&](int s, int wp, int rp) {
        if (active) {
            const int t = s - l;
            if (t >= 0 && t < T) {
                // This half reads only its own input row (half the LDS traffic).
                float in[12];
                {
                    float4* iv = (float4*)in;
                    const float4* src = hsel ? (const float4*)&buf[l + 1][rp][0]
                                             : (const float4*)&buf[l][rp][0];
                    iv[0] = src[0]; iv[1] = src[1]; iv[2] = src[2];
                }

                v2f acc2[4];
                #pragma unroll
                for (int g = 0; g < 4; ++g) {
                    v2f a; a[0] = bias[g]; a[1] = 0.0f; acc2[g] = a;
                }
                #pragma unroll
                for (int p = 0; p < 5; ++p) {
                    v2f ip; ip[0] = in[2 * p]; ip[1] = in[2 * p + 1];
                    #pragma unroll
                    for (int g = 0; g < 4; ++g) acc2[g] = v2fma(w2[g][p], ip, acc2[g]);
                }

                // Keep own partial of the kept gate; send own partial of the
                // partner's gate. Kept: hsel0 {i=0, g=2}, hsel1 {f=1, o=3}.
                float p_if = acc2[hsel ? 1 : 0][0] + acc2[hsel ? 1 : 0][1]; // keep i / f
                float p_go = acc2[hsel ? 3 : 2][0] + acc2[hsel ? 3 : 2][1]; // keep g / o
                float s_if = acc2[hsel ? 0 : 1][0] + acc2[hsel ? 0 : 1][1]; // send f / i
                float s_go = acc2[hsel ? 2 : 3][0] + acc2[hsel ? 2 : 3][1]; // send o / g
                const float e0 = p_if + lane_swap(s_if);  // hsel0: e(i), hsel1: e(f)
                const float e1 = p_go + lane_swap(s_go);  // hsel0: e(g), hsel1: e(o)

                const float s0 = sigmoid_f(e0);           // sig(i) / sig(f)
                const float e  = __expf(k2 * e1);
                const float v1 = A2 - B2 * __builtin_amdgcn_rcpf(1.0f + e);
                                                          // tanh(g) / sig(o)
                const float a  = s0 * v1;                 // hsel0: sig(i)*tanh(g)
                const float recv_s = lane_swap(s0);       // hsel0 gets sig(f)
                c = fmaf(recv_s, c, a);                   // real c on hsel0 only
                const float tc = tanh_f(c);
                const float recv_t = lane_swap(tc);       // hsel1 gets tanh(c)
                const float hval = v1 * recv_t;           // hsel1: sig(o)*tanh(c)

                if (hsel) {
                    buf[l + 1][wp][j] = hval;
                    if (l == L - 1) out[(size_t)t * BH + boff] = hval;
                }
            }
            // Layer-0 x-side lanes stage x(s+1) from the register pipe.
            if (l == 0 && !hsel && (s + 1) < T) {
                buf[0][wp][j] = xcur[s & (CH - 1)];
            }
        }
        __syncthreads();
    };

    for (int k = 0; k < NCHUNK; ++k) {
        const int s0 = k * CH;
        // Issue next chunk's x loads; the vmcnt drain at the next barrier
        // then happens once per CH steps instead of every step.
        if (active && l == 0 && !hsel) {
            #pragma unroll
            for (int i = 0; i < CH; ++i) {
                int t = s0 + CH + 1 + i;
                t = t < T ? t : T - 1;
                xnext[i] = x[(size_t)t * BH + boff];
            }
        }
        #pragma unroll
        for (int u = 0; u < CH; u += 2) {    // s0 even -> parities compile-time
            step(s0 + u, 0, 1);
            step(s0 + u + 1, 1, 0);
        }
        if (active && l == 0 && !hsel) {
            #pragma unroll
            for (int i = 0; i < CH; ++i) xcur[i] = xnext[i];
        }
    }

    // Finals: layer l's h(T-1) was written at s=T-1+l -> parity (l+1)&1 (T even).
    if (active && !hsel) {
        hn[(l * B + b) * H + j] = buf[l + 1][(l + 1) & 1][j];
        cn[(l * B + b) * H + j] = c;
    }
}

} // namespace

extern "C" void kernel_launch(void* const* d_in, const int* in_sizes, int n_in,
                              void* d_out, int out_size, void* d_ws, size_t ws_size,
                              hipStream_t stream) {
    (void)in_sizes; (void)n_in; (void)d_ws; (void)ws_size; (void)out_size;
    const float* x   = (const float*)d_in[0];
    const float* hp  = (const float*)d_in[1];
    const float* cp  = (const float*)d_in[2];
    const float* Wih = (const float*)d_in[3];
    const float* Whh = (const float*)d_in[4];
    const float* bih = (const float*)d_in[5];
    const float* bhh = (const float*)d_in[6];

    float* out = (float*)d_out;
    float* hn  = out + (size_t)T * B * H;
    float* cn  = hn + (size_t)L * B * H;

    lstm_pipeline<<<dim3(B), dim3(NTHREADS), 0, stream>>>(
        x, hp, cp, Wih, Whh, bih, bhh, out, hn, cn);
}

// Round 9
// 509.310 us; speedup vs baseline: 2.8017x; 2.8017x over previous
//
#include <hip/hip_runtime.h>

namespace {

constexpr int T = 1024;
constexpr int B = 1024;
constexpr int L = 10;
constexpr int H = 10;
constexpr int NTHREADS = 128;       // 2 waves: wave0 = layers 0-5, wave1 = layers 6-9
constexpr int U = 4;                // timesteps per interval (barrier amortization)
constexpr int NWIN = T / U;         // 256 windows
constexpr int NINT = NWIN + L - 1;  // 265 intervals
constexpr int BH = B * H;
constexpr int WSLOT = 88;           // per-thread LDS weight slot (80 w + 4 bias + pad)

using v2f = __attribute__((ext_vector_type(2))) float;

__device__ __forceinline__ v2f v2fma(v2f a, v2f b, v2f c) {
    return __builtin_elementwise_fma(a, b, c);   // v_pk_fma_f32
}

__device__ __forceinline__ float sigmoid_f(float x) {
    return __builtin_amdgcn_rcpf(1.0f + __expf(-x));
}
__device__ __forceinline__ float tanh_f(float x) {
    return 1.0f - 2.0f * __builtin_amdgcn_rcpf(1.0f + __expf(2.0f * x));
}

__global__
__attribute__((amdgpu_flat_work_group_size(NTHREADS, NTHREADS)))
__attribute__((amdgpu_waves_per_eu(2, 2)))   // 256-VGPR budget
void lstm_pipeline(const float* __restrict__ x,    // [T,B,H]
                   const float* __restrict__ hp,   // [L,B,H]
                   const float* __restrict__ cp,   // [L,B,H]
                   const float* __restrict__ Wih,  // [L,4H,H]
                   const float* __restrict__ Whh,  // [L,4H,H]
                   const float* __restrict__ bih,  // [L,4H]
                   const float* __restrict__ bhh,  // [L,4H]
                   float* __restrict__ out,        // [T,B,H]
                   float* __restrict__ hn,         // [L,B,H]
                   float* __restrict__ cn)         // [L,B,H]
{
    // Weight staging area: global loads are freely rematerialized by LLVM
    // (rounds 4-6: VGPR stuck at 76/88 with in-loop reloads); ds_read cannot
    // be remat'd across barriers, so regs loaded from here stay resident.
    __shared__ __align__(16) float wlds[L * H * WSLOT];   // 35.2 KB
    // buf[l] = U input rows for layer l, parity double-buffered per interval.
    __shared__ __align__(16) float buf[L + 1][2][U][12];  // 4.2 KB
    // Wave-private recurrent h rows (layer l touched only by its own wave;
    // same-wave ds ops are program-ordered -> no barrier inside an interval).
    __shared__ __align__(16) float hbuf[L][12];           // 0.5 KB

    const int tid = threadIdx.x;
    const int wv = tid >> 6, ln = tid & 63;
    const bool active = (wv == 0) ? (ln < 60) : (ln < 40);
    const int lidx = (wv == 0) ? ln : 60 + ln;     // 0..99 when active
    const int l = active ? lidx / 10 : L - 1;
    const int j = active ? lidx % 10 : H - 1;
    const int b = blockIdx.x;
    const int boff = b * H + j;

    // ---- one-time: stage weights to LDS ----
    if (active) {
        float* slot = &wlds[(l * H + j) * WSLOT];
        #pragma unroll
        for (int g = 0; g < 4; ++g) {
            const size_t row = (size_t)(l * 4 * H + g * H + j);
            const float* wr = Wih + row * H;
            const float* hr = Whh + row * H;
            #pragma unroll
            for (int i = 0; i < H; ++i) slot[g * H + i] = wr[i];
            #pragma unroll
            for (int i = 0; i < H; ++i) slot[40 + g * H + i] = hr[i];
            slot[80 + g] = bih[row] + bhh[row];
        }
    }
    __syncthreads();

    // ---- read back into registers (un-remat-able) ----
    v2f wi2[4][5], wh2[4][5];
    float bias[4];
    {
        const float* slot = &wlds[(active ? l * H + j : 0) * WSLOT];
        #pragma unroll
        for (int g = 0; g < 4; ++g) {
            #pragma unroll
            for (int p = 0; p < 5; ++p) {
                v2f a; a[0] = slot[g * H + 2 * p];      a[1] = slot[g * H + 2 * p + 1];      wi2[g][p] = a;
                v2f d; d[0] = slot[40 + g * H + 2 * p]; d[1] = slot[40 + g * H + 2 * p + 1]; wh2[g][p] = d;
            }
            bias[g] = slot[80 + g];
        }
    }

    float h = 0.0f, c = 0.0f;
    float xcur[U], xnext[U];
    if (active) {
        h = hp[(l * B + b) * H + j];
        c = cp[(l * B + b) * H + j];
        hbuf[l][j] = h;                       // h(-1)
        if (l == 0) {
            #pragma unroll
            for (int u = 0; u < U; ++u) buf[0][1][u][j] = x[(size_t)u * BH + boff];       // window 0
            #pragma unroll
            for (int u = 0; u < U; ++u) xcur[u] = x[(size_t)(U + u) * BH + boff];         // window 1
        }
    }
    __syncthreads();

    for (int k = 0; k < NINT; ++k) {
        const int wp = k & 1, rp = wp ^ 1;
        // Issue x loads for window k+2 (drain absorbed at this interval's barrier).
        if (active && l == 0 && (k + 2) < NWIN) {
            #pragma unroll
            for (int u = 0; u < U; ++u)
                xnext[u] = x[(size_t)((k + 2) * U + u) * BH + boff];
        }
        const unsigned w = (unsigned)(k - l);
        if (active && w < (unsigned)NWIN) {
            const int t0 = (int)w * U;
            #pragma unroll
            for (int u = 0; u < U; ++u) {
                float xin[12], hrow[12];
                {
                    const float4* xs = (const float4*)&buf[l][rp][u][0];
                    ((float4*)xin)[0] = xs[0]; ((float4*)xin)[1] = xs[1]; ((float4*)xin)[2] = xs[2];
                    const float4* hs = (const float4*)&hbuf[l][0];
                    ((float4*)hrow)[0] = hs[0]; ((float4*)hrow)[1] = hs[1]; ((float4*)hrow)[2] = hs[2];
                }
                v2f acc[4];
                #pragma unroll
                for (int g = 0; g < 4; ++g) { v2f a; a[0] = bias[g]; a[1] = 0.0f; acc[g] = a; }
                #pragma unroll
                for (int p = 0; p < 5; ++p) {
                    v2f xp; xp[0] = xin[2 * p]; xp[1] = xin[2 * p + 1];
                    #pragma unroll
                    for (int g = 0; g < 4; ++g) acc[g] = v2fma(wi2[g][p], xp, acc[g]);
                }
                #pragma unroll
                for (int p = 0; p < 5; ++p) {
                    v2f hh; hh[0] = hrow[2 * p]; hh[1] = hrow[2 * p + 1];
                    #pragma unroll
                    for (int g = 0; g < 4; ++g) acc[g] = v2fma(wh2[g][p], hh, acc[g]);
                }
                const float ig = sigmoid_f(acc[0][0] + acc[0][1]);
                const float fg = sigmoid_f(acc[1][0] + acc[1][1]);
                const float gg = tanh_f(acc[2][0] + acc[2][1]);
                const float og = sigmoid_f(acc[3][0] + acc[3][1]);
                c = fmaf(fg, c, ig * gg);
                h = og * tanh_f(c);

                hbuf[l][j] = h;               // same-wave readers at u+1
                if (l < L - 1) buf[l + 1][wp][u][j] = h;
                else out[(size_t)(t0 + u) * BH + boff] = h;
            }
        }
        // Stage x window k+1 for next interval.
        if (active && l == 0 && (k + 1) < NWIN) {
            #pragma unroll
            for (int u = 0; u < U; ++u) buf[0][wp][u][j] = xcur[u];
            #pragma unroll
            for (int u = 0; u < U; ++u) xcur[u] = xnext[u];
        }
        __syncthreads();
    }

    if (active) {
        hn[(l * B + b) * H + j] = h;          // h(T-1), in-register
        cn[(l * B + b) * H + j] = c;
    }
}

} // namespace

extern "C" void kernel_launch(void* const* d_in, const int* in_sizes, int n_in,
                              void* d_out, int out_size, void* d_ws, size_t ws_size,
                              hipStream_t stream) {
    (void)in_sizes; (void)n_in; (void)d_ws; (void)ws_size; (void)out_size;
    const float* x   = (const float*)d_in[0];
    const float* hp  = (const float*)d_in[1];
    const float* cp  = (const float*)d_in[2];
    const float* Wih = (const float*)d_in[3];
    const float* Whh = (const float*)d_in[4];
    const float* bih = (const float*)d_in[5];
    const float* bhh = (const float*)d_in[6];

    float* out = (float*)d_out;
    float* hn  = out + (size_t)T * B * H;
    float* cn  = hn + (size_t)L * B * H;

    lstm_pipeline<<<dim3(B), dim3(NTHREADS), 0, stream>>>(
        x, hp, cp, Wih, Whh, bih, bhh, out, hn, cn);
}

// Round 10
// 499.844 us; speedup vs baseline: 2.8548x; 1.0189x over previous
//
#include <hip/hip_runtime.h>

namespace {

constexpr int T = 1024;
constexpr int B = 1024;
constexpr int L = 10;
constexpr int H = 10;
constexpr int NTHREADS = 128;       // 2 waves: wave0 = layers 0-5, wave1 = layers 6-9
constexpr int U = 4;                // timesteps per interval
constexpr int NWIN = T / U;         // 256 windows
constexpr int NINT = NWIN + L - 1;  // 265 intervals
constexpr int BH = B * H;
constexpr int WSLOT = 84;           // 80 weights + 4 fused biases per (l,j)

using v2f = __attribute__((ext_vector_type(2))) float;

__device__ __forceinline__ v2f v2fma(v2f a, v2f b, v2f c) {
    return __builtin_elementwise_fma(a, b, c);   // v_pk_fma_f32
}
__device__ __forceinline__ void pin2(v2f& v) { asm volatile("" : "+v"(v)); }
__device__ __forceinline__ void pin1(float& v) { asm volatile("" : "+v"(v)); }

__device__ __forceinline__ float sigmoid_f(float x) {
    return __builtin_amdgcn_rcpf(1.0f + __expf(-x));
}
__device__ __forceinline__ float tanh_f(float x) {
    return 1.0f - 2.0f * __builtin_amdgcn_rcpf(1.0f + __expf(2.0f * x));
}

__global__
__attribute__((amdgpu_flat_work_group_size(NTHREADS, NTHREADS)))
__attribute__((amdgpu_waves_per_eu(1)))   // permission for up to 512 VGPRs
void lstm_pipeline(const float* __restrict__ x,    // [T,B,H]
                   const float* __restrict__ hp,   // [L,B,H]
                   const float* __restrict__ cp,   // [L,B,H]
                   const float* __restrict__ Wih,  // [L,4H,H]
                   const float* __restrict__ Whh,  // [L,4H,H]
                   const float* __restrict__ bih,  // [L,4H]
                   const float* __restrict__ bhh,  // [L,4H]
                   float* __restrict__ out,        // [T,B,H]
                   float* __restrict__ hn,         // [L,B,H]
                   float* __restrict__ cn)         // [L,B,H]
{
    __shared__ __align__(16) float wlds[L * H * WSLOT];   // 33.6 KB staging
    __shared__ __align__(16) float buf[L + 1][2][U][12];  // layer-input windows
    __shared__ __align__(16) float hbuf[L][12];           // wave-local h rows

    const int tid = threadIdx.x;
    const int wv = tid >> 6, ln = tid & 63;
    // Every lane gets a valid (l,j); lanes beyond the 100 primaries duplicate
    // existing work (same inputs -> same values -> same addresses; benign).
    int lidx;
    if (wv == 0) lidx = (ln < 60) ? ln : (ln - 10);            // dup l=5,j=0..3
    else         lidx = (ln < 40) ? (60 + ln) : (90 + (ln - 40) % 10);  // dup l=9
    const int l = lidx / 10;
    const int j = lidx % 10;
    const int b = blockIdx.x;
    const int boff = b * H + j;

    // ---- one-time: stage this thread's weights to LDS (unconditional) ----
    {
        float* slot = &wlds[lidx * WSLOT];
        #pragma unroll
        for (int g = 0; g < 4; ++g) {
            const int row = l * 4 * H + g * H + j;
            const float* wr = Wih + (size_t)row * H;
            const float* hr = Whh + (size_t)row * H;
            #pragma unroll
            for (int i = 0; i < H; ++i) slot[g * H + i] = wr[i];
            #pragma unroll
            for (int i = 0; i < H; ++i) slot[40 + g * H + i] = hr[i];
            slot[80 + g] = bih[row] + bhh[row];
        }
    }
    __syncthreads();

    // ---- read back into pinned registers ----
    v2f wi2[4][5], wh2[4][5];
    float bias[4];
    {
        const float* slot = &wlds[lidx * WSLOT];
        #pragma unroll
        for (int g = 0; g < 4; ++g) {
            #pragma unroll
            for (int p = 0; p < 5; ++p) {
                wi2[g][p] = *(const v2f*)&slot[g * H + 2 * p];
                wh2[g][p] = *(const v2f*)&slot[40 + g * H + 2 * p];
            }
            bias[g] = slot[80 + g];
        }
    }
    #pragma unroll
    for (int g = 0; g < 4; ++g) {
        #pragma unroll
        for (int p = 0; p < 5; ++p) { pin2(wi2[g][p]); pin2(wh2[g][p]); }
        pin1(bias[g]);
    }

    float h = hp[(l * B + b) * H + j];
    float c = cp[(l * B + b) * H + j];
    hbuf[l][j] = h;                           // h(-1)

    float xcur[U], xnext[U];
    if (lidx < 10) {                          // layer-0 primaries stage x
        #pragma unroll
        for (int u = 0; u < U; ++u) buf[0][1][u][j] = x[(size_t)u * BH + boff];
        #pragma unroll
        for (int u = 0; u < U; ++u) xcur[u] = x[(size_t)(U + u) * BH + boff];
    }
    __syncthreads();

    auto interval = [&](int k, int wp, int rp) {
        // Prefetch x window k+2 (drain amortized to once per interval).
        if (lidx < 10 && (k + 2) < NWIN) {
            #pragma unroll
            for (int u = 0; u < U; ++u)
                xnext[u] = x[(size_t)((k + 2) * U + u) * BH + boff];
        }
        const unsigned w = (unsigned)(k - l);
        if (w < (unsigned)NWIN) {
            float hv[U];
            #pragma unroll
            for (int u = 0; u < U; ++u) {
                float xin[10], hin[10];
                {
                    const float* xr = &buf[l][rp][u][0];
                    *(float4*)&xin[0] = *(const float4*)(xr);
                    *(float4*)&xin[4] = *(const float4*)(xr + 4);
                    *(float2*)&xin[8] = *(const float2*)(xr + 8);
                    const float* hr = &hbuf[l][0];
                    *(float4*)&hin[0] = *(const float4*)(hr);
                    *(float4*)&hin[4] = *(const float4*)(hr + 4);
                    *(float2*)&hin[8] = *(const float2*)(hr + 8);
                }
                v2f a0, a1, a2, a3;
                a0[0] = bias[0]; a0[1] = 0.0f;
                a1[0] = bias[1]; a1[1] = 0.0f;
                a2[0] = bias[2]; a2[1] = 0.0f;
                a3[0] = bias[3]; a3[1] = 0.0f;
                #pragma unroll
                for (int p = 0; p < 5; ++p) {
                    v2f xp; xp[0] = xin[2 * p]; xp[1] = xin[2 * p + 1];
                    a0 = v2fma(wi2[0][p], xp, a0);
                    a1 = v2fma(wi2[1][p], xp, a1);
                    a2 = v2fma(wi2[2][p], xp, a2);
                    a3 = v2fma(wi2[3][p], xp, a3);
                }
                #pragma unroll
                for (int p = 0; p < 5; ++p) {
                    v2f hh; hh[0] = hin[2 * p]; hh[1] = hin[2 * p + 1];
                    a0 = v2fma(wh2[0][p], hh, a0);
                    a1 = v2fma(wh2[1][p], hh, a1);
                    a2 = v2fma(wh2[2][p], hh, a2);
                    a3 = v2fma(wh2[3][p], hh, a3);
                }
                const float ig = sigmoid_f(a0[0] + a0[1]);
                const float fg = sigmoid_f(a1[0] + a1[1]);
                const float gg = tanh_f(a2[0] + a2[1]);
                const float og = sigmoid_f(a3[0] + a3[1]);
                c = fmaf(fg, c, ig * gg);
                h = og * tanh_f(c);

                hbuf[l][j] = h;               // same-wave readers at u+1
                buf[l + 1][wp][u][j] = h;     // l=9 writes pad row 10 (unused)
                hv[u] = h;
            }
            if (l == L - 1) {                 // batched out-stores (dups benign)
                const int t0 = (int)w * U;
                #pragma unroll
                for (int u = 0; u < U; ++u)
                    out[(size_t)(t0 + u) * BH + boff] = hv[u];
            }
        }
        // Stage x window k+1 for the next interval.
        if (lidx < 10 && (k + 1) < NWIN) {
            #pragma unroll
            for (int u = 0; u < U; ++u) buf[0][wp][u][j] = xcur[u];
            #pragma unroll
            for (int u = 0; u < U; ++u) xcur[u] = xnext[u];
        }
        __syncthreads();
    };

    for (int kk = 0; kk < NINT + 1; kk += 2) {   // literal parities
        interval(kk, 0, 1);
        interval(kk + 1, 1, 0);
    }

    hn[(l * B + b) * H + j] = h;   // duplicates store identical values
    cn[(l * B + b) * H + j] = c;
}

} // namespace

extern "C" void kernel_launch(void* const* d_in, const int* in_sizes, int n_in,
                              void* d_out, int out_size, void* d_ws, size_t ws_size,
                              hipStream_t stream) {
    (void)in_sizes; (void)n_in; (void)d_ws; (void)ws_size; (void)out_size;
    const float* x   = (const float*)d_in[0];
    const float* hp  = (const float*)d_in[1];
    const float* cp  = (const float*)d_in[2];
    const float* Wih = (const float*)d_in[3];
    const float* Whh = (const float*)d_in[4];
    const float* bih = (const float*)d_in[5];
    const float* bhh = (const float*)d_in[6];

    float* out = (float*)d_out;
    float* hn  = out + (size_t)T * B * H;
    float* cn  = hn + (size_t)L * B * H;

    lstm_pipeline<<<dim3(B), dim3(NTHREADS), 0, stream>>>(
        x, hp, cp, Wih, Whh, bih, bhh, out, hn, cn);
}